// Round 4
// baseline (354.729 us; speedup 1.0000x reference)
//
#include <hip/hip_runtime.h>

#define NHEADS 16
#define HD 128
#define LSEQ 2048
#define NBATCH 2
#define HDIM 2048
#define NQKV 6144
#define SCALE 0.08838834764831845f

typedef __attribute__((ext_vector_type(8))) short bfx8;
typedef __attribute__((ext_vector_type(4))) short bfx4;
typedef __attribute__((ext_vector_type(4))) float f32x4;

__device__ __forceinline__ unsigned short f2bf(float x) {
  unsigned u = __float_as_uint(x);
  u += 0x7fffu + ((u >> 16) & 1u);
  return (unsigned short)(u >> 16);
}
__device__ __forceinline__ float bf2f(unsigned short u) {
  return __uint_as_float(((unsigned)u) << 16);
}
__device__ __forceinline__ void gload_lds16(const void* g, void* l) {
  __builtin_amdgcn_global_load_lds(
      (const __attribute__((address_space(1))) unsigned int*)g,
      (__attribute__((address_space(3))) unsigned int*)l, 16, 0, 0);
}

// ---------------- cast f32 -> bf16 (vectorized) ----------------
__global__ __launch_bounds__(256) void cast_bf16_kernel(
    const float* __restrict__ in, unsigned short* __restrict__ out, int n4) {
  int i = blockIdx.x * 256 + threadIdx.x;
  if (i >= n4) return;
  float4 v = ((const float4*)in)[i];
  bfx4 o;
  o[0] = (short)f2bf(v.x);
  o[1] = (short)f2bf(v.y);
  o[2] = (short)f2bf(v.z);
  o[3] = (short)f2bf(v.w);
  ((bfx4*)out)[i] = o;
}

// ---------------- GEMM 256x256 tile, BK=64, 8 waves, 4-phase/K-tile ----------------
// C[M,N] = A[M,K] * B[N,K]^T. T1 XCD swizzle, T2 both-sides LDS swizzle,
// T3/T4 phase-split with raw barriers + tile-boundary vmcnt, T5 setprio.
template<bool BF16OUT>
__global__ __launch_bounds__(512, 2) void gemm256_kernel(
    const unsigned short* __restrict__ A, const unsigned short* __restrict__ B,
    void* __restrict__ Cout, int M, int N, int K) {
  __shared__ unsigned short lA[2][256 * 64];
  __shared__ unsigned short lB[2][256 * 64];
  const int tid = threadIdx.x;
  const int w = tid >> 6, lane = tid & 63;
  const int g = lane >> 4, ln = lane & 15;
  const int nmt = M >> 8, nnt = N >> 8;
  const int nwg = nmt * nnt;
  const int bid = blockIdx.x;
  const int swz = (bid & 7) * (nwg >> 3) + (bid >> 3);  // nwg % 8 == 0
  const int bm = (swz / nnt) * 256, bn = (swz % nnt) * 256;
  const int wm = (w >> 2) * 128, wn = (w & 3) * 64;

  auto STAGE = [&](int buf, int k0, int q) {
    int rid = q * 64 + w * 8 + (lane >> 3);   // tile row 0..255
    int slot = lane & 7;                      // 16B chunk within 128B row
    gload_lds16(A + (size_t)(bm + rid) * K + k0 + ((slot ^ (rid & 7)) << 3),
                &lA[buf][(q * 512 + w * 64) * 8]);
    gload_lds16(B + (size_t)(bn + rid) * K + k0 + ((slot ^ (rid & 7)) << 3),
                &lB[buf][(q * 512 + w * 64) * 8]);
  };

  f32x4 acc[8][4];
#pragma unroll
  for (int i = 0; i < 8; ++i)
#pragma unroll
    for (int j = 0; j < 4; ++j) acc[i][j] = (f32x4){0.f, 0.f, 0.f, 0.f};

  // prologue: stage tile 0
#pragma unroll
  for (int q = 0; q < 4; ++q) STAGE(0, 0, q);
  asm volatile("s_waitcnt vmcnt(0)" ::: "memory");
  asm volatile("s_barrier" ::: "memory");

  const int nt = K >> 6;
  for (int t = 0; t < nt; ++t) {
    const int cur = t & 1;
    const char* lAc = (const char*)lA[cur];
    const char* lBc = (const char*)lB[cur];
    const int k0n = (t + 1) << 6;
    bfx8 bfrag[4][2];
#pragma unroll
    for (int ph = 0; ph < 4; ++ph) {
      if (t + 1 < nt) STAGE(cur ^ 1, k0n, ph);
      bfx8 afrag[2][2];
#pragma unroll
      for (int mi = 0; mi < 2; ++mi)
#pragma unroll
        for (int kk = 0; kk < 2; ++kk)
          afrag[mi][kk] = *(const bfx8*)(lAc + (wm + ph * 32 + mi * 16 + ln) * 128 +
                                         (((kk * 4 + g) ^ (ln & 7)) << 4));
      if (ph == 0) {
#pragma unroll
        for (int nf = 0; nf < 4; ++nf)
#pragma unroll
          for (int kk = 0; kk < 2; ++kk)
            bfrag[nf][kk] = *(const bfx8*)(lBc + (wn + nf * 16 + ln) * 128 +
                                           (((kk * 4 + g) ^ (ln & 7)) << 4));
      }
      asm volatile("s_waitcnt lgkmcnt(0)" ::: "memory");
      __builtin_amdgcn_sched_barrier(0);
      __builtin_amdgcn_s_setprio(1);
#pragma unroll
      for (int kk = 0; kk < 2; ++kk)
#pragma unroll
        for (int mi = 0; mi < 2; ++mi)
#pragma unroll
          for (int nf = 0; nf < 4; ++nf)
            acc[ph * 2 + mi][nf] = __builtin_amdgcn_mfma_f32_16x16x32_bf16(
                afrag[mi][kk], bfrag[nf][kk], acc[ph * 2 + mi][nf], 0, 0, 0);
      __builtin_amdgcn_s_setprio(0);
      if (ph < 3) asm volatile("s_barrier" ::: "memory");
    }
    // tile boundary: only next-tile stages outstanding -> near-free drain
    asm volatile("s_waitcnt vmcnt(0)" ::: "memory");
    asm volatile("s_barrier" ::: "memory");
  }

#pragma unroll
  for (int mf = 0; mf < 8; ++mf) {
    int row0 = bm + wm + mf * 16 + g * 4;
#pragma unroll
    for (int nf = 0; nf < 4; ++nf) {
      int col = bn + wn + nf * 16 + ln;
#pragma unroll
      for (int r = 0; r < 4; ++r) {
        if constexpr (BF16OUT)
          ((unsigned short*)Cout)[(size_t)(row0 + r) * N + col] = f2bf(acc[mf][nf][r]);
        else
          ((float*)Cout)[(size_t)(row0 + r) * N + col] = acc[mf][nf][r];
      }
    }
  }
}

// ---------------- GEMM 128x128 (2-phase) for out-proj ----------------
template<bool BF16OUT>
__global__ __launch_bounds__(256) void gemm_bt_kernel(
    const unsigned short* __restrict__ A, const unsigned short* __restrict__ B,
    void* __restrict__ Cout, int M, int N, int K) {
  __shared__ unsigned short lA[128 * 64];
  __shared__ unsigned short lB[128 * 64];
  const int tid = threadIdx.x;
  const int w = tid >> 6, lane = tid & 63;
  const int g = lane >> 4, ln = lane & 15;
  const int bm = blockIdx.x * 128, bn = blockIdx.y * 128;
  const int wm = (w >> 1) * 64, wn = (w & 1) * 64;
  const int srow = lane >> 3;
  const int scol = (lane & 7) * 8;

  f32x4 acc[4][4];
#pragma unroll
  for (int i = 0; i < 4; ++i)
#pragma unroll
    for (int j = 0; j < 4; ++j) acc[i][j] = (f32x4){0.f, 0.f, 0.f, 0.f};

  for (int k0 = 0; k0 < K; k0 += 64) {
#pragma unroll
    for (int p = 0; p < 4; ++p) {
      int seg = p * 4 + w;
      int row = seg * 8 + srow;
      const unsigned short* gA = A + (size_t)(bm + row) * K + (k0 + scol);
      const unsigned short* gB = B + (size_t)(bn + row) * K + (k0 + scol);
      gload_lds16(gA, lA + seg * 512);
      gload_lds16(gB, lB + seg * 512);
    }
    __syncthreads();
#pragma unroll
    for (int kk = 0; kk < 2; ++kk) {
      bfx8 af[4], bfr[4];
#pragma unroll
      for (int i = 0; i < 4; ++i)
        af[i] = *(const bfx8*)(lA + (wm + i * 16 + ln) * 64 + kk * 32 + g * 8);
#pragma unroll
      for (int j = 0; j < 4; ++j)
        bfr[j] = *(const bfx8*)(lB + (wn + j * 16 + ln) * 64 + kk * 32 + g * 8);
#pragma unroll
      for (int i = 0; i < 4; ++i)
#pragma unroll
        for (int j = 0; j < 4; ++j)
          acc[i][j] = __builtin_amdgcn_mfma_f32_16x16x32_bf16(af[i], bfr[j], acc[i][j], 0, 0, 0);
    }
    __syncthreads();
  }
#pragma unroll
  for (int i = 0; i < 4; ++i) {
    int row0 = bm + wm + i * 16 + g * 4;
#pragma unroll
    for (int j = 0; j < 4; ++j) {
      int col = bn + wn + j * 16 + ln;
#pragma unroll
      for (int r = 0; r < 4; ++r) {
        if constexpr (BF16OUT)
          ((unsigned short*)Cout)[(size_t)(row0 + r) * N + col] = f2bf(acc[i][j][r]);
        else
          ((float*)Cout)[(size_t)(row0 + r) * N + col] = acc[i][j][r];
      }
    }
  }
}

// ---------------- RoPE + scatter ----------------
__global__ __launch_bounds__(256) void rope_scatter_kernel(
    const unsigned short* __restrict__ qkv,
    unsigned short* __restrict__ Qo, unsigned short* __restrict__ Ko,
    unsigned short* __restrict__ Vt) {
  __shared__ unsigned short lV[32 * 128];
  const int bh = blockIdx.x;
  const int l0 = blockIdx.y * 32;
  const int b = bh >> 4, h = bh & 15;
  const int tid = threadIdx.x;
#pragma unroll
  for (int it = 0; it < 2; ++it) {
    int idx = it * 256 + tid;
    int ll = idx >> 4;
    int dq = idx & 15;
    int l = l0 + ll;
    const unsigned short* row = qkv + (size_t)(b * LSEQ + l) * NQKV + h * HD;
    bfx4 qlo = *(const bfx4*)(row + dq * 4);
    bfx4 qhi = *(const bfx4*)(row + 64 + dq * 4);
    bfx4 klo = *(const bfx4*)(row + 2048 + dq * 4);
    bfx4 khi = *(const bfx4*)(row + 2048 + 64 + dq * 4);
    bfx4 vlo = *(const bfx4*)(row + 4096 + dq * 4);
    bfx4 vhi = *(const bfx4*)(row + 4096 + 64 + dq * 4);
    bfx4 oqlo, oqhi, oklo, okhi;
#pragma unroll
    for (int e = 0; e < 4; ++e) {
      int d2 = dq * 4 + e;
      float invf = exp2f(-(float)d2 * 0.2076205059304601f);
      float fr = (float)l * invf;
      float s, c;
      sincosf(fr, &s, &c);
      float xq1 = bf2f((unsigned short)qlo[e]), xq2 = bf2f((unsigned short)qhi[e]);
      oqlo[e] = (short)f2bf(xq1 * c - xq2 * s);
      oqhi[e] = (short)f2bf(xq2 * c + xq1 * s);
      float xk1 = bf2f((unsigned short)klo[e]), xk2 = bf2f((unsigned short)khi[e]);
      oklo[e] = (short)f2bf(xk1 * c - xk2 * s);
      okhi[e] = (short)f2bf(xk2 * c + xk1 * s);
    }
    size_t obase = ((size_t)bh * LSEQ + l) * HD;
    *(bfx4*)(Qo + obase + dq * 4) = oqlo;
    *(bfx4*)(Qo + obase + 64 + dq * 4) = oqhi;
    *(bfx4*)(Ko + obase + dq * 4) = oklo;
    *(bfx4*)(Ko + obase + 64 + dq * 4) = okhi;
    *(bfx4*)(lV + ll * 128 + dq * 4) = vlo;
    *(bfx4*)(lV + ll * 128 + 64 + dq * 4) = vhi;
  }
  __syncthreads();
#pragma unroll
  for (int it = 0; it < 16; ++it) {
    int idx = it * 256 + tid;
    int d = idx >> 5;
    int ll = idx & 31;
    Vt[((size_t)bh * HD + d) * LSEQ + l0 + ll] = lV[ll * 128 + d];
  }
}

// ---------------- Flash attention: 8 waves, q-tile 128, KV chunk 64, LDS-staged ----------------
__global__ __launch_bounds__(512, 4) void flash_kernel(
    const unsigned short* __restrict__ Q, const unsigned short* __restrict__ K,
    const unsigned short* __restrict__ Vt, unsigned short* __restrict__ O) {
  __shared__ unsigned short lKs[2][64 * 128];
  __shared__ unsigned short lVs[2][128 * 64];
  __shared__ unsigned short lP[8][16 * 40];
  const int bh = blockIdx.x;
  const int qt = 15 - (int)blockIdx.y;
  const int q0 = qt * 128;
  const int tid = threadIdx.x;
  const int w = tid >> 6, lane = tid & 63;
  const int g = lane >> 4, ln = lane & 15;
  const int q0w = q0 + w * 16;
  const unsigned short* Qb = Q + (size_t)bh * LSEQ * HD;
  const unsigned short* Kb = K + (size_t)bh * LSEQ * HD;
  const unsigned short* Vb = Vt + (size_t)bh * HD * LSEQ;
  unsigned short* Pw = lP[w];

  auto STAGE = [&](int buf, int kv0s) {
#pragma unroll
    for (int s = 0; s < 2; ++s) {
      int rl = s * 32 + w * 4 + (lane >> 4);
      int slot = lane & 15;
      const unsigned short* src =
          Kb + (size_t)(kv0s + rl) * HD + ((slot ^ (rl & 15)) * 8);
      gload_lds16(src, &lKs[buf][(s * 8192 + w * 1024) / 2]);
    }
#pragma unroll
    for (int s = 0; s < 2; ++s) {
      int d = s * 64 + w * 8 + (lane >> 3);
      int slot = lane & 7;
      const unsigned short* src =
          Vb + (size_t)d * LSEQ + kv0s + ((slot ^ (d & 7)) * 8);
      gload_lds16(src, &lVs[buf][(s * 8192 + w * 1024) / 2]);
    }
  };

  bfx8 qf[4];
#pragma unroll
  for (int c = 0; c < 4; ++c)
    qf[c] = *(const bfx8*)(Qb + (size_t)(q0w + ln) * HD + c * 32 + g * 8);

  f32x4 o[8];
#pragma unroll
  for (int dt = 0; dt < 8; ++dt) o[dt] = (f32x4){0.f, 0.f, 0.f, 0.f};
  float m = -1e30f, sum = 0.f;
  const int qg = q0w + ln;
  const int nch = 2 * qt + 2;

  STAGE(0, 0);
  __syncthreads();

  for (int ch = 0; ch < nch; ++ch) {
    const int kv0 = ch * 64;
    const int cur = ch & 1;
    if (ch + 1 < nch) STAGE(cur ^ 1, kv0 + 64);

    if (kv0 <= q0w + 15) {
      const char* lK0 = (const char*)lKs[cur];
      const char* lV0 = (const char*)lVs[cur];
      f32x4 s4[4];
#pragma unroll
      for (int kt = 0; kt < 4; ++kt) s4[kt] = (f32x4){0.f, 0.f, 0.f, 0.f};
#pragma unroll
      for (int c = 0; c < 4; ++c) {
        const int cbb = c * 64 + g * 16;
#pragma unroll
        for (int kt = 0; kt < 4; ++kt) {
          bfx8 kf = *(const bfx8*)(lK0 + (kt * 16 + ln) * 256 + (cbb ^ (ln << 4)));
          s4[kt] = __builtin_amdgcn_mfma_f32_16x16x32_bf16(kf, qf[c], s4[kt], 0, 0, 0);
        }
      }
      float tm = -1e30f;
      if (kv0 + 63 <= q0w) {
#pragma unroll
        for (int kt = 0; kt < 4; ++kt)
#pragma unroll
          for (int r = 0; r < 4; ++r) {
            s4[kt][r] *= SCALE;
            tm = fmaxf(tm, s4[kt][r]);
          }
      } else {
#pragma unroll
        for (int kt = 0; kt < 4; ++kt)
#pragma unroll
          for (int r = 0; r < 4; ++r) {
            int kvr = kv0 + kt * 16 + 4 * g + r;
            float v = (kvr <= qg) ? s4[kt][r] * SCALE : -1e30f;
            s4[kt][r] = v;
            tm = fmaxf(tm, v);
          }
      }
      tm = fmaxf(tm, __shfl_xor(tm, 16));
      tm = fmaxf(tm, __shfl_xor(tm, 32));
      float f = 1.f;
      const bool dorescale = !__all(tm <= m + 8.f);
      if (dorescale) {
        float mnew = fmaxf(m, tm);
        f = __expf(m - mnew);
        m = mnew;
      }
      float ts = 0.f;
      bfx4 pb4[4];
#pragma unroll
      for (int kt = 0; kt < 4; ++kt)
#pragma unroll
        for (int r = 0; r < 4; ++r) {
          float p = __expf(s4[kt][r] - m);
          ts += p;
          pb4[kt][r] = (short)f2bf(p);
        }
      ts += __shfl_xor(ts, 16);
      ts += __shfl_xor(ts, 32);
      sum = sum * f + ts;
      float fr0 = 1.f, fr1 = 1.f, fr2 = 1.f, fr3 = 1.f;
      if (dorescale) {
        fr0 = __shfl(f, 4 * g + 0);
        fr1 = __shfl(f, 4 * g + 1);
        fr2 = __shfl(f, 4 * g + 2);
        fr3 = __shfl(f, 4 * g + 3);
      }
#pragma unroll
      for (int kvh = 0; kvh < 2; ++kvh) {
        asm volatile("s_waitcnt lgkmcnt(0)" ::: "memory");
        __builtin_amdgcn_sched_barrier(0);
        *(bfx4*)(Pw + ln * 40 + 4 * g) = pb4[2 * kvh];
        *(bfx4*)(Pw + ln * 40 + 16 + 4 * g) = pb4[2 * kvh + 1];
        asm volatile("s_waitcnt lgkmcnt(0)" ::: "memory");
        __builtin_amdgcn_sched_barrier(0);
        bfx8 pf = *(const bfx8*)(Pw + ln * 40 + g * 8);
        if (kvh == 0 && dorescale) {
#pragma unroll
          for (int dt = 0; dt < 8; ++dt) {
            o[dt][0] *= fr0; o[dt][1] *= fr1; o[dt][2] *= fr2; o[dt][3] *= fr3;
          }
        }
#pragma unroll
        for (int dt = 0; dt < 8; ++dt) {
          bfx8 vf = *(const bfx8*)(lV0 + (dt * 16 + ln) * 128 +
                                   ((kvh * 64 + g * 16) ^ ((ln & 7) << 4)));
          o[dt] = __builtin_amdgcn_mfma_f32_16x16x32_bf16(pf, vf, o[dt], 0, 0, 0);
        }
      }
    }
    __syncthreads();
  }

  float inv = 1.f / sum;
  float ir0 = __shfl(inv, 4 * g + 0);
  float ir1 = __shfl(inv, 4 * g + 1);
  float ir2 = __shfl(inv, 4 * g + 2);
  float ir3 = __shfl(inv, 4 * g + 3);
  const int b = bh >> 4, h = bh & 15;
  unsigned short* Ob = O + (size_t)b * LSEQ * HDIM + h * HD;
#pragma unroll
  for (int dt = 0; dt < 8; ++dt) {
    Ob[(size_t)(q0w + 4 * g + 0) * HDIM + dt * 16 + ln] = f2bf(o[dt][0] * ir0);
    Ob[(size_t)(q0w + 4 * g + 1) * HDIM + dt * 16 + ln] = f2bf(o[dt][1] * ir1);
    Ob[(size_t)(q0w + 4 * g + 2) * HDIM + dt * 16 + ln] = f2bf(o[dt][2] * ir2);
    Ob[(size_t)(q0w + 4 * g + 3) * HDIM + dt * 16 + ln] = f2bf(o[dt][3] * ir3);
  }
}

// ---------------- launch ----------------
extern "C" void kernel_launch(void* const* d_in, const int* in_sizes, int n_in,
                              void* d_out, int out_size, void* d_ws, size_t ws_size,
                              hipStream_t stream) {
  const float* x = (const float*)d_in[0];
  const float* w_qkv = (const float*)d_in[1];
  const float* w_o = (const float*)d_in[2];
  float* out = (float*)d_out;
  char* ws = (char*)d_ws;

  unsigned short* xb    = (unsigned short*)(ws + 0);
  unsigned short* wqkvb = (unsigned short*)(ws + 16777216);
  unsigned short* wob   = (unsigned short*)(ws + 41943040);
  unsigned short* qkvb  = (unsigned short*)(ws + 50331648);
  unsigned short* qb    = (unsigned short*)(ws + 100663296);
  unsigned short* kb    = (unsigned short*)(ws + 117440512);
  unsigned short* vtb   = (unsigned short*)(ws + 134217728);
  unsigned short* attnb = (unsigned short*)(ws + 0);

  cast_bf16_kernel<<<8388608 / 4 / 256, 256, 0, stream>>>(x, xb, 8388608 / 4);
  cast_bf16_kernel<<<12582912 / 4 / 256, 256, 0, stream>>>(w_qkv, wqkvb, 12582912 / 4);
  cast_bf16_kernel<<<4194304 / 4 / 256, 256, 0, stream>>>(w_o, wob, 4194304 / 4);

  gemm256_kernel<true><<<(4096 / 256) * (6144 / 256), 512, 0, stream>>>(
      xb, wqkvb, (void*)qkvb, 4096, 6144, 2048);

  rope_scatter_kernel<<<dim3(32, 64), 256, 0, stream>>>(qkvb, qb, kb, vtb);

  flash_kernel<<<dim3(32, 16), 512, 0, stream>>>(qb, kb, vtb, attnb);

  gemm_bt_kernel<false><<<dim3(4096 / 128, 2048 / 128), 256, 0, stream>>>(
      attnb, wob, (void*)out, 4096, 2048, 2048);
}

// Round 5
// 301.466 us; speedup vs baseline: 1.1767x; 1.1767x over previous
//
#include <hip/hip_runtime.h>

#define NHEADS 16
#define HD 128
#define LSEQ 2048
#define NBATCH 2
#define HDIM 2048
#define NQKV 6144
#define SCALE 0.08838834764831845f

typedef __attribute__((ext_vector_type(8))) short bfx8;
typedef __attribute__((ext_vector_type(4))) short bfx4;
typedef __attribute__((ext_vector_type(4))) float f32x4;

__device__ __forceinline__ unsigned short f2bf(float x) {
  unsigned u = __float_as_uint(x);
  u += 0x7fffu + ((u >> 16) & 1u);
  return (unsigned short)(u >> 16);
}
__device__ __forceinline__ float bf2f(unsigned short u) {
  return __uint_as_float(((unsigned)u) << 16);
}
__device__ __forceinline__ void gload_lds16(const void* g, void* l) {
  __builtin_amdgcn_global_load_lds(
      (const __attribute__((address_space(1))) unsigned int*)g,
      (__attribute__((address_space(3))) unsigned int*)l, 16, 0, 0);
}

// ---------------- cast f32 -> bf16 (vectorized) ----------------
__global__ __launch_bounds__(256) void cast_bf16_kernel(
    const float* __restrict__ in, unsigned short* __restrict__ out, int n4) {
  int i = blockIdx.x * 256 + threadIdx.x;
  if (i >= n4) return;
  float4 v = ((const float4*)in)[i];
  bfx4 o;
  o[0] = (short)f2bf(v.x);
  o[1] = (short)f2bf(v.y);
  o[2] = (short)f2bf(v.z);
  o[3] = (short)f2bf(v.w);
  ((bfx4*)out)[i] = o;
}

// ---------------- GEMM 256x256, BK=64, 8 waves, 4-phase + COUNTED vmcnt (T1-T5) ----------------
// Stage order/tile (into buf^1): ph0: Bq0,Bq1; ph1: Bq2,Bq3; ph2: Aq0,Aq2; ph3: Aq1,Aq3.
// Waits: ph3-tail vmcnt(2) [B+Aq0,q2 of next tile landed], ph1-tail vmcnt(4) [Aq1,q3 landed].
// Final tile peeled semantics via `more`: ph1-tail vmcnt(0), no stages.
template<bool BF16OUT>
__global__ __launch_bounds__(512, 1) void gemm256_kernel(
    const unsigned short* __restrict__ A, const unsigned short* __restrict__ B,
    void* __restrict__ Cout, int M, int N, int K) {
  __shared__ unsigned short lA[2][256 * 64];
  __shared__ unsigned short lB[2][256 * 64];
  const int tid = threadIdx.x;
  const int w = tid >> 6, lane = tid & 63;
  const int g = lane >> 4, ln = lane & 15;
  const int nmt = M >> 8, nnt = N >> 8;
  const int nwg = nmt * nnt;
  const int bid = blockIdx.x;
  const int swz = (bid & 7) * (nwg >> 3) + (bid >> 3);  // nwg % 8 == 0
  const int bm = (swz / nnt) * 256, bn = (swz % nnt) * 256;
  const int wm = (w >> 2) * 128, wn = (w & 3) * 64;
  const unsigned short* At = A + (size_t)bm * K;
  const unsigned short* Bt = B + (size_t)bn * K;

  // stage one 64-row quarter q of one matrix (2 KB/wave, 8 KB total per call)
  auto STG = [&](const unsigned short* src, unsigned short* dst, int q, int k0) {
    int rid = q * 64 + w * 8 + (lane >> 3);
    int slot = lane & 7;
    gload_lds16(src + (size_t)rid * K + k0 + ((slot ^ (rid & 7)) << 3),
                dst + (size_t)(q * 4096 + w * 512));
  };

  f32x4 acc[8][4];
#pragma unroll
  for (int i = 0; i < 8; ++i)
#pragma unroll
    for (int j = 0; j < 4; ++j) acc[i][j] = (f32x4){0.f, 0.f, 0.f, 0.f};

  // prologue: tile 0 -> buf 0, exact order B0,B1,B2,B3,A0,A2,A1,A3
  STG(Bt, lB[0], 0, 0); STG(Bt, lB[0], 1, 0);
  STG(Bt, lB[0], 2, 0); STG(Bt, lB[0], 3, 0);
  STG(At, lA[0], 0, 0); STG(At, lA[0], 2, 0);
  STG(At, lA[0], 1, 0); STG(At, lA[0], 3, 0);
  asm volatile("s_waitcnt vmcnt(2)" ::: "memory");
  __builtin_amdgcn_s_barrier();

  const int nt = K >> 6;
  bfx8 bfrag[4][2];
  for (int t = 0; t < nt; ++t) {
    const int cur = t & 1;
    const char* lAc = (const char*)lA[cur];
    const char* lBc = (const char*)lB[cur];
    unsigned short* sA = lA[cur ^ 1];
    unsigned short* sB = lB[cur ^ 1];
    const int k1 = (t + 1) << 6;
    const bool more = (t + 1 < nt);
#pragma unroll
    for (int ph = 0; ph < 4; ++ph) {
      if (more) {
        if (ph == 0)      { STG(Bt, sB, 0, k1); STG(Bt, sB, 1, k1); }
        else if (ph == 1) { STG(Bt, sB, 2, k1); STG(Bt, sB, 3, k1); }
        else if (ph == 2) { STG(At, sA, 0, k1); STG(At, sA, 2, k1); }
        else              { STG(At, sA, 1, k1); STG(At, sA, 3, k1); }
      }
      bfx8 afrag[2][2];
#pragma unroll
      for (int mi = 0; mi < 2; ++mi)
#pragma unroll
        for (int kk = 0; kk < 2; ++kk)
          afrag[mi][kk] = *(const bfx8*)(lAc + (wm + (ph * 2 + mi) * 16 + ln) * 128 +
                                         (((kk * 4 + g) ^ (ln & 7)) << 4));
      if (ph == 0) {
#pragma unroll
        for (int nf = 0; nf < 4; ++nf)
#pragma unroll
          for (int kk = 0; kk < 2; ++kk)
            bfrag[nf][kk] = *(const bfx8*)(lBc + (wn + nf * 16 + ln) * 128 +
                                           (((kk * 4 + g) ^ (ln & 7)) << 4));
      }
      __builtin_amdgcn_s_barrier();
      asm volatile("s_waitcnt lgkmcnt(0)" ::: "memory");
      __builtin_amdgcn_sched_barrier(0);
      __builtin_amdgcn_s_setprio(1);
#pragma unroll
      for (int kk = 0; kk < 2; ++kk)
#pragma unroll
        for (int mi = 0; mi < 2; ++mi)
#pragma unroll
          for (int nf = 0; nf < 4; ++nf)
            acc[ph * 2 + mi][nf] = __builtin_amdgcn_mfma_f32_16x16x32_bf16(
                afrag[mi][kk], bfrag[nf][kk], acc[ph * 2 + mi][nf], 0, 0, 0);
      __builtin_amdgcn_s_setprio(0);
      if (ph == 1) {
        if (more) asm volatile("s_waitcnt vmcnt(4)" ::: "memory");
        else      asm volatile("s_waitcnt vmcnt(0)" ::: "memory");
      } else if (ph == 3 && more) {
        asm volatile("s_waitcnt vmcnt(2)" ::: "memory");
      }
      __builtin_amdgcn_sched_barrier(0);
      __builtin_amdgcn_s_barrier();
    }
  }

#pragma unroll
  for (int mf = 0; mf < 8; ++mf) {
    int row0 = bm + wm + mf * 16 + g * 4;
#pragma unroll
    for (int nf = 0; nf < 4; ++nf) {
      int col = bn + wn + nf * 16 + ln;
#pragma unroll
      for (int r = 0; r < 4; ++r) {
        if constexpr (BF16OUT)
          ((unsigned short*)Cout)[(size_t)(row0 + r) * N + col] = f2bf(acc[mf][nf][r]);
        else
          ((float*)Cout)[(size_t)(row0 + r) * N + col] = acc[mf][nf][r];
      }
    }
  }
}

// ---------------- GEMM 128x128 (2-phase) for out-proj ----------------
template<bool BF16OUT>
__global__ __launch_bounds__(256) void gemm_bt_kernel(
    const unsigned short* __restrict__ A, const unsigned short* __restrict__ B,
    void* __restrict__ Cout, int M, int N, int K) {
  __shared__ unsigned short lA[128 * 64];
  __shared__ unsigned short lB[128 * 64];
  const int tid = threadIdx.x;
  const int w = tid >> 6, lane = tid & 63;
  const int g = lane >> 4, ln = lane & 15;
  const int bm = blockIdx.x * 128, bn = blockIdx.y * 128;
  const int wm = (w >> 1) * 64, wn = (w & 1) * 64;
  const int srow = lane >> 3;
  const int scol = (lane & 7) * 8;

  f32x4 acc[4][4];
#pragma unroll
  for (int i = 0; i < 4; ++i)
#pragma unroll
    for (int j = 0; j < 4; ++j) acc[i][j] = (f32x4){0.f, 0.f, 0.f, 0.f};

  for (int k0 = 0; k0 < K; k0 += 64) {
#pragma unroll
    for (int p = 0; p < 4; ++p) {
      int seg = p * 4 + w;
      int row = seg * 8 + srow;
      const unsigned short* gA = A + (size_t)(bm + row) * K + (k0 + scol);
      const unsigned short* gB = B + (size_t)(bn + row) * K + (k0 + scol);
      gload_lds16(gA, lA + seg * 512);
      gload_lds16(gB, lB + seg * 512);
    }
    __syncthreads();
#pragma unroll
    for (int kk = 0; kk < 2; ++kk) {
      bfx8 af[4], bfr[4];
#pragma unroll
      for (int i = 0; i < 4; ++i)
        af[i] = *(const bfx8*)(lA + (wm + i * 16 + ln) * 64 + kk * 32 + g * 8);
#pragma unroll
      for (int j = 0; j < 4; ++j)
        bfr[j] = *(const bfx8*)(lB + (wn + j * 16 + ln) * 64 + kk * 32 + g * 8);
#pragma unroll
      for (int i = 0; i < 4; ++i)
#pragma unroll
        for (int j = 0; j < 4; ++j)
          acc[i][j] = __builtin_amdgcn_mfma_f32_16x16x32_bf16(af[i], bfr[j], acc[i][j], 0, 0, 0);
    }
    __syncthreads();
  }
#pragma unroll
  for (int i = 0; i < 4; ++i) {
    int row0 = bm + wm + i * 16 + g * 4;
#pragma unroll
    for (int j = 0; j < 4; ++j) {
      int col = bn + wn + j * 16 + ln;
#pragma unroll
      for (int r = 0; r < 4; ++r) {
        if constexpr (BF16OUT)
          ((unsigned short*)Cout)[(size_t)(row0 + r) * N + col] = f2bf(acc[i][j][r]);
        else
          ((float*)Cout)[(size_t)(row0 + r) * N + col] = acc[i][j][r];
      }
    }
  }
}

// ---------------- RoPE + scatter ----------------
__global__ __launch_bounds__(256) void rope_scatter_kernel(
    const unsigned short* __restrict__ qkv,
    unsigned short* __restrict__ Qo, unsigned short* __restrict__ Ko,
    unsigned short* __restrict__ Vt) {
  __shared__ unsigned short lV[32 * 128];
  const int bh = blockIdx.x;
  const int l0 = blockIdx.y * 32;
  const int b = bh >> 4, h = bh & 15;
  const int tid = threadIdx.x;
#pragma unroll
  for (int it = 0; it < 2; ++it) {
    int idx = it * 256 + tid;
    int ll = idx >> 4;
    int dq = idx & 15;
    int l = l0 + ll;
    const unsigned short* row = qkv + (size_t)(b * LSEQ + l) * NQKV + h * HD;
    bfx4 qlo = *(const bfx4*)(row + dq * 4);
    bfx4 qhi = *(const bfx4*)(row + 64 + dq * 4);
    bfx4 klo = *(const bfx4*)(row + 2048 + dq * 4);
    bfx4 khi = *(const bfx4*)(row + 2048 + 64 + dq * 4);
    bfx4 vlo = *(const bfx4*)(row + 4096 + dq * 4);
    bfx4 vhi = *(const bfx4*)(row + 4096 + 64 + dq * 4);
    bfx4 oqlo, oqhi, oklo, okhi;
#pragma unroll
    for (int e = 0; e < 4; ++e) {
      int d2 = dq * 4 + e;
      float invf = exp2f(-(float)d2 * 0.2076205059304601f);
      float fr = (float)l * invf;
      float s, c;
      sincosf(fr, &s, &c);
      float xq1 = bf2f((unsigned short)qlo[e]), xq2 = bf2f((unsigned short)qhi[e]);
      oqlo[e] = (short)f2bf(xq1 * c - xq2 * s);
      oqhi[e] = (short)f2bf(xq2 * c + xq1 * s);
      float xk1 = bf2f((unsigned short)klo[e]), xk2 = bf2f((unsigned short)khi[e]);
      oklo[e] = (short)f2bf(xk1 * c - xk2 * s);
      okhi[e] = (short)f2bf(xk2 * c + xk1 * s);
    }
    size_t obase = ((size_t)bh * LSEQ + l) * HD;
    *(bfx4*)(Qo + obase + dq * 4) = oqlo;
    *(bfx4*)(Qo + obase + 64 + dq * 4) = oqhi;
    *(bfx4*)(Ko + obase + dq * 4) = oklo;
    *(bfx4*)(Ko + obase + 64 + dq * 4) = okhi;
    *(bfx4*)(lV + ll * 128 + dq * 4) = vlo;
    *(bfx4*)(lV + ll * 128 + 64 + dq * 4) = vhi;
  }
  __syncthreads();
#pragma unroll
  for (int it = 0; it < 16; ++it) {
    int idx = it * 256 + tid;
    int d = idx >> 5;
    int ll = idx & 31;
    Vt[((size_t)bh * HD + d) * LSEQ + l0 + ll] = lV[ll * 128 + d];
  }
}

// ---------------- Flash attention: 8 waves, q-tile 128, KV chunk 64, LDS-staged ----------------
__global__ __launch_bounds__(512, 4) void flash_kernel(
    const unsigned short* __restrict__ Q, const unsigned short* __restrict__ K,
    const unsigned short* __restrict__ Vt, unsigned short* __restrict__ O) {
  __shared__ unsigned short lKs[2][64 * 128];
  __shared__ unsigned short lVs[2][128 * 64];
  __shared__ unsigned short lP[8][16 * 40];
  const int bh = blockIdx.x;
  const int qt = 15 - (int)blockIdx.y;
  const int q0 = qt * 128;
  const int tid = threadIdx.x;
  const int w = tid >> 6, lane = tid & 63;
  const int g = lane >> 4, ln = lane & 15;
  const int q0w = q0 + w * 16;
  const unsigned short* Qb = Q + (size_t)bh * LSEQ * HD;
  const unsigned short* Kb = K + (size_t)bh * LSEQ * HD;
  const unsigned short* Vb = Vt + (size_t)bh * HD * LSEQ;
  unsigned short* Pw = lP[w];

  auto STAGE = [&](int buf, int kv0s) {
#pragma unroll
    for (int s = 0; s < 2; ++s) {
      int rl = s * 32 + w * 4 + (lane >> 4);
      int slot = lane & 15;
      const unsigned short* src =
          Kb + (size_t)(kv0s + rl) * HD + ((slot ^ (rl & 15)) * 8);
      gload_lds16(src, &lKs[buf][(s * 8192 + w * 1024) / 2]);
    }
#pragma unroll
    for (int s = 0; s < 2; ++s) {
      int d = s * 64 + w * 8 + (lane >> 3);
      int slot = lane & 7;
      const unsigned short* src =
          Vb + (size_t)d * LSEQ + kv0s + ((slot ^ (d & 7)) * 8);
      gload_lds16(src, &lVs[buf][(s * 8192 + w * 1024) / 2]);
    }
  };

  bfx8 qf[4];
#pragma unroll
  for (int c = 0; c < 4; ++c)
    qf[c] = *(const bfx8*)(Qb + (size_t)(q0w + ln) * HD + c * 32 + g * 8);

  f32x4 o[8];
#pragma unroll
  for (int dt = 0; dt < 8; ++dt) o[dt] = (f32x4){0.f, 0.f, 0.f, 0.f};
  float m = -1e30f, sum = 0.f;
  const int qg = q0w + ln;
  const int nch = 2 * qt + 2;

  STAGE(0, 0);
  __syncthreads();

  for (int ch = 0; ch < nch; ++ch) {
    const int kv0 = ch * 64;
    const int cur = ch & 1;
    if (ch + 1 < nch) STAGE(cur ^ 1, kv0 + 64);

    if (kv0 <= q0w + 15) {
      const char* lK0 = (const char*)lKs[cur];
      const char* lV0 = (const char*)lVs[cur];
      f32x4 s4[4];
#pragma unroll
      for (int kt = 0; kt < 4; ++kt) s4[kt] = (f32x4){0.f, 0.f, 0.f, 0.f};
#pragma unroll
      for (int c = 0; c < 4; ++c) {
        const int cbb = c * 64 + g * 16;
#pragma unroll
        for (int kt = 0; kt < 4; ++kt) {
          bfx8 kf = *(const bfx8*)(lK0 + (kt * 16 + ln) * 256 + (cbb ^ (ln << 4)));
          s4[kt] = __builtin_amdgcn_mfma_f32_16x16x32_bf16(kf, qf[c], s4[kt], 0, 0, 0);
        }
      }
      float tm = -1e30f;
      if (kv0 + 63 <= q0w) {
#pragma unroll
        for (int kt = 0; kt < 4; ++kt)
#pragma unroll
          for (int r = 0; r < 4; ++r) {
            s4[kt][r] *= SCALE;
            tm = fmaxf(tm, s4[kt][r]);
          }
      } else {
#pragma unroll
        for (int kt = 0; kt < 4; ++kt)
#pragma unroll
          for (int r = 0; r < 4; ++r) {
            int kvr = kv0 + kt * 16 + 4 * g + r;
            float v = (kvr <= qg) ? s4[kt][r] * SCALE : -1e30f;
            s4[kt][r] = v;
            tm = fmaxf(tm, v);
          }
      }
      tm = fmaxf(tm, __shfl_xor(tm, 16));
      tm = fmaxf(tm, __shfl_xor(tm, 32));
      float f = 1.f;
      const bool dorescale = !__all(tm <= m + 8.f);
      if (dorescale) {
        float mnew = fmaxf(m, tm);
        f = __expf(m - mnew);
        m = mnew;
      }
      float ts = 0.f;
      bfx4 pb4[4];
#pragma unroll
      for (int kt = 0; kt < 4; ++kt)
#pragma unroll
        for (int r = 0; r < 4; ++r) {
          float p = __expf(s4[kt][r] - m);
          ts += p;
          pb4[kt][r] = (short)f2bf(p);
        }
      ts += __shfl_xor(ts, 16);
      ts += __shfl_xor(ts, 32);
      sum = sum * f + ts;
      float fr0 = 1.f, fr1 = 1.f, fr2 = 1.f, fr3 = 1.f;
      if (dorescale) {
        fr0 = __shfl(f, 4 * g + 0);
        fr1 = __shfl(f, 4 * g + 1);
        fr2 = __shfl(f, 4 * g + 2);
        fr3 = __shfl(f, 4 * g + 3);
      }
#pragma unroll
      for (int kvh = 0; kvh < 2; ++kvh) {
        asm volatile("s_waitcnt lgkmcnt(0)" ::: "memory");
        __builtin_amdgcn_sched_barrier(0);
        *(bfx4*)(Pw + ln * 40 + 4 * g) = pb4[2 * kvh];
        *(bfx4*)(Pw + ln * 40 + 16 + 4 * g) = pb4[2 * kvh + 1];
        asm volatile("s_waitcnt lgkmcnt(0)" ::: "memory");
        __builtin_amdgcn_sched_barrier(0);
        bfx8 pf = *(const bfx8*)(Pw + ln * 40 + g * 8);
        if (kvh == 0 && dorescale) {
#pragma unroll
          for (int dt = 0; dt < 8; ++dt) {
            o[dt][0] *= fr0; o[dt][1] *= fr1; o[dt][2] *= fr2; o[dt][3] *= fr3;
          }
        }
#pragma unroll
        for (int dt = 0; dt < 8; ++dt) {
          bfx8 vf = *(const bfx8*)(lV0 + (dt * 16 + ln) * 128 +
                                   ((kvh * 64 + g * 16) ^ ((ln & 7) << 4)));
          o[dt] = __builtin_amdgcn_mfma_f32_16x16x32_bf16(pf, vf, o[dt], 0, 0, 0);
        }
      }
    }
    __syncthreads();
  }

  float inv = 1.f / sum;
  float ir0 = __shfl(inv, 4 * g + 0);
  float ir1 = __shfl(inv, 4 * g + 1);
  float ir2 = __shfl(inv, 4 * g + 2);
  float ir3 = __shfl(inv, 4 * g + 3);
  const int b = bh >> 4, h = bh & 15;
  unsigned short* Ob = O + (size_t)b * LSEQ * HDIM + h * HD;
#pragma unroll
  for (int dt = 0; dt < 8; ++dt) {
    Ob[(size_t)(q0w + 4 * g + 0) * HDIM + dt * 16 + ln] = f2bf(o[dt][0] * ir0);
    Ob[(size_t)(q0w + 4 * g + 1) * HDIM + dt * 16 + ln] = f2bf(o[dt][1] * ir1);
    Ob[(size_t)(q0w + 4 * g + 2) * HDIM + dt * 16 + ln] = f2bf(o[dt][2] * ir2);
    Ob[(size_t)(q0w + 4 * g + 3) * HDIM + dt * 16 + ln] = f2bf(o[dt][3] * ir3);
  }
}

// ---------------- launch ----------------
extern "C" void kernel_launch(void* const* d_in, const int* in_sizes, int n_in,
                              void* d_out, int out_size, void* d_ws, size_t ws_size,
                              hipStream_t stream) {
  const float* x = (const float*)d_in[0];
  const float* w_qkv = (const float*)d_in[1];
  const float* w_o = (const float*)d_in[2];
  float* out = (float*)d_out;
  char* ws = (char*)d_ws;

  unsigned short* xb    = (unsigned short*)(ws + 0);
  unsigned short* wqkvb = (unsigned short*)(ws + 16777216);
  unsigned short* wob   = (unsigned short*)(ws + 41943040);
  unsigned short* qkvb  = (unsigned short*)(ws + 50331648);
  unsigned short* qb    = (unsigned short*)(ws + 100663296);
  unsigned short* kb    = (unsigned short*)(ws + 117440512);
  unsigned short* vtb   = (unsigned short*)(ws + 134217728);
  unsigned short* attnb = (unsigned short*)(ws + 0);

  cast_bf16_kernel<<<8388608 / 4 / 256, 256, 0, stream>>>(x, xb, 8388608 / 4);
  cast_bf16_kernel<<<12582912 / 4 / 256, 256, 0, stream>>>(w_qkv, wqkvb, 12582912 / 4);
  cast_bf16_kernel<<<4194304 / 4 / 256, 256, 0, stream>>>(w_o, wob, 4194304 / 4);

  gemm256_kernel<true><<<(4096 / 256) * (6144 / 256), 512, 0, stream>>>(
      xb, wqkvb, (void*)qkvb, 4096, 6144, 2048);

  rope_scatter_kernel<<<dim3(32, 64), 256, 0, stream>>>(qkvb, qb, kb, vtb);

  flash_kernel<<<dim3(32, 16), 512, 0, stream>>>(qb, kb, vtb, attnb);

  gemm_bt_kernel<false><<<dim3(4096 / 128, 2048 / 128), 256, 0, stream>>>(
      attnb, wob, (void*)out, 4096, 2048, 2048);
}